// Round 1
// baseline (881.558 us; speedup 1.0000x reference)
//
#include <hip/hip_runtime.h>

#define NS   12     // n_state
#define HID  128
#define NC   13     // augmented cols: [V | J0..J11]
#define GPB  4      // samples per block
#define LW   64     // LDS row width = GPB*16 slots

// ---------------------------------------------------------------------------
// Weight transpose: ws holds Wt0[12][128], Wt1[128][128], Wt2[.., Wt3[..
// so the main loop's per-h slice Wt[h][o..o+31] is contiguous (s_load-able).
// ---------------------------------------------------------------------------
__global__ __launch_bounds__(256) void transpose_w(
    const float* __restrict__ W0, const float* __restrict__ W1,
    const float* __restrict__ W2, const float* __restrict__ W3,
    float* __restrict__ ws)
{
  int t = blockIdx.x * 256 + threadIdx.x;
  const int S0 = NS * HID;    // 1536
  const int S  = HID * HID;   // 16384
  if (t < S0) {
    int h = t >> 7, o = t & 127;
    ws[t] = W0[o * NS + h];
  } else if (t < S0 + S) {
    int i = t - S0; int h = i >> 7, o = i & 127;
    ws[t] = W1[o * HID + h];
  } else if (t < S0 + 2 * S) {
    int i = t - (S0 + S); int h = i >> 7, o = i & 127;
    ws[t] = W2[o * HID + h];
  } else if (t < S0 + 3 * S) {
    int i = t - (S0 + 2 * S); int h = i >> 7, o = i & 127;
    ws[t] = W3[o * HID + h];
  }
}

// fast tanh via v_exp_f32; clamp avoids inf/inf. abs err ~1e-6.
__device__ __forceinline__ float fast_tanh(float v) {
  float vc = fminf(fmaxf(v, -15.0f), 15.0f);
  float e  = __expf(vc + vc);
  return (e - 1.0f) * __builtin_amdgcn_rcpf(e + 1.0f);
}

// One linear layer over the augmented LDS tile.
// Xin/Xout: [K][LW] / [HID][LW].  wt: transposed weights [K][HID].
// Each wave computes rows [wbase, wbase+32). W slice is wave-uniform -> s_load.
template<int K, bool ACT>
__device__ __forceinline__ void layer_pass(
    const float* __restrict__ Xin, float* __restrict__ Xout,
    const float* __restrict__ wt, const float* __restrict__ bias,
    int wbase, int lane, int c)
{
  float acc[32];
  #pragma unroll
  for (int r = 0; r < 32; ++r) acc[r] = 0.0f;

  #pragma unroll 2
  for (int h = 0; h < K; ++h) {
    float x = Xin[h * LW + lane];                 // stride-1 across lanes
    const float* __restrict__ wr = wt + h * HID + wbase;  // wave-uniform
    #pragma unroll
    for (int r = 0; r < 32; ++r) acc[r] = fmaf(wr[r], x, acc[r]);
  }

  #pragma unroll
  for (int r = 0; r < 32; ++r) {
    float bv = bias[wbase + r];   // wave-uniform
    float res;
    if (ACT) {
      float t = fast_tanh(acc[r] + bv);           // valid on c==0 lanes
      float s = 1.0f - t * t;
      // broadcast s from the c==0 lane of this sample's 16-lane group
      int si = __builtin_amdgcn_ds_swizzle(__float_as_int(s), 0x0010);
      float sb = __int_as_float(si);
      res = (c == 0) ? t : acc[r] * sb;
    } else {
      res = (c == 0) ? (acc[r] + bv) : acc[r];
    }
    Xout[(wbase + r) * LW + lane] = res;
  }
}

__global__ __launch_bounds__(256, 2) void mlp_jac_kernel(
    const float* __restrict__ state,
    const float* __restrict__ safe_m, const float* __restrict__ safe_l,
    const float* __restrict__ ws,
    const float* __restrict__ b0, const float* __restrict__ b1,
    const float* __restrict__ b2, const float* __restrict__ b3,
    const float* __restrict__ Wout, const float* __restrict__ bout,
    float* __restrict__ out, int bs)
{
  __shared__ float Xa[HID * LW];   // 32 KB
  __shared__ float Xb[HID * LW];   // 32 KB
  __shared__ float red[4 * LW];    // 1 KB

  const int tid  = threadIdx.x;
  const int lane = tid & 63;
  const int wid  = __builtin_amdgcn_readfirstlane(tid >> 6);
  const int wbase = wid * 32;
  const int c = lane & 15;
  const int g = lane >> 4;

  // ---- build X0[12][64]: col0 = x_norm, cols 1..12 = diag(1/x_range) ----
  for (int i = tid; i < NS * LW; i += 256) {
    int h  = i >> 6;
    int sl = i & 63;
    int gg = sl >> 4, cc = sl & 15;
    float m = safe_m[h], l = safe_l[h];
    float inv = 2.0f / (m - l);          // 1 / x_range
    float v = 0.0f;
    int sidx = blockIdx.x * GPB + gg;
    if (cc == 0) {
      float cen = 0.5f * (m + l);
      float sv = (sidx < bs) ? state[sidx * NS + h] : 0.0f;
      v = (sv - cen) * inv;
    } else if (cc <= NS && h == cc - 1) {
      v = inv;
    }
    Xa[i] = v;
  }
  __syncthreads();

  const float* Wt0 = ws;
  const float* Wt1 = ws + NS * HID;
  const float* Wt2 = Wt1 + HID * HID;
  const float* Wt3 = Wt2 + HID * HID;

  layer_pass<NS,  true >(Xa, Xb, Wt0, b0, wbase, lane, c);
  __syncthreads();
  layer_pass<HID, true >(Xb, Xa, Wt1, b1, wbase, lane, c);
  __syncthreads();
  layer_pass<HID, true >(Xa, Xb, Wt2, b2, wbase, lane, c);
  __syncthreads();
  layer_pass<HID, false>(Xb, Xa, Wt3, b3, wbase, lane, c);
  __syncthreads();

  // ---- output row: out = Wout @ X4 (+ bout on col 0). Split h over waves.
  float part = 0.0f;
  #pragma unroll 4
  for (int h = 0; h < 32; ++h) {
    int hh = wbase + h;
    part = fmaf(Wout[hh], Xa[hh * LW + lane], part);
  }
  red[wid * LW + lane] = part;
  __syncthreads();

  if (wid == 0 && c < NC) {
    float tot = red[lane] + red[LW + lane] + red[2 * LW + lane] + red[3 * LW + lane];
    if (c == 0) tot += bout[0];
    int sidx = blockIdx.x * GPB + g;
    if (sidx < bs) out[sidx * NC + c] = tot;
  }
}

extern "C" void kernel_launch(void* const* d_in, const int* in_sizes, int n_in,
                              void* d_out, int out_size, void* d_ws, size_t ws_size,
                              hipStream_t stream)
{
  const float* state  = (const float*)d_in[0];
  const float* safe_m = (const float*)d_in[1];
  const float* safe_l = (const float*)d_in[2];
  const float* W0   = (const float*)d_in[3];
  const float* b0   = (const float*)d_in[4];
  const float* W1   = (const float*)d_in[5];
  const float* b1   = (const float*)d_in[6];
  const float* W2   = (const float*)d_in[7];
  const float* b2   = (const float*)d_in[8];
  const float* W3   = (const float*)d_in[9];
  const float* b3   = (const float*)d_in[10];
  const float* Wout = (const float*)d_in[11];
  const float* bout = (const float*)d_in[12];
  float* ws  = (float*)d_ws;
  float* out = (float*)d_out;

  const int bs = in_sizes[0] / NS;

  const int total_t = NS * HID + 3 * HID * HID;   // 50688
  transpose_w<<<(total_t + 255) / 256, 256, 0, stream>>>(W0, W1, W2, W3, ws);

  const int nblocks = (bs + GPB - 1) / GPB;       // 4096
  mlp_jac_kernel<<<nblocks, 256, 0, stream>>>(state, safe_m, safe_l, ws,
      b0, b1, b2, b3, Wout, bout, out, bs);
}

// Round 2
// 207.244 us; speedup vs baseline: 4.2537x; 4.2537x over previous
//
#include <hip/hip_runtime.h>

#define NS 12
#define HID 128
#define SPB 16            // samples per block
#define RB  256           // rows per block = SPB*16 (V + 12 J + 3 pad per sample)

typedef __attribute__((ext_vector_type(8))) short bf8_t;   // 8 bf16 (4 VGPR)
typedef __attribute__((ext_vector_type(4))) float f4_t;    // C/D frag

// ws layout (u32 units): W0hi@0 (2048), W0lo@2048; W_i (i=1..3):
// hi @ 4096+(i-1)*16384 (8192), lo @ hi+8192.  Total 53248 u32 = 208 KB.
#define O_W0H 0
#define O_W0L 2048
#define O_WH(i) (4096 + (i) * 16384)
#define O_WL(i) (O_WH(i) + 8192)

__device__ __forceinline__ unsigned f2bf_u(float f) {
  unsigned u = __float_as_uint(f);
  return (u + 0x7FFFu + ((u >> 16) & 1u)) >> 16;     // RNE
}
__device__ __forceinline__ float bf2f(unsigned h) { return __uint_as_float(h << 16); }
__device__ __forceinline__ unsigned packhl(float x) {   // lo16=hi-bf16, hi16=lo-bf16
  unsigned h = f2bf_u(x);
  unsigned l = f2bf_u(x - bf2f(h));
  return h | (l << 16);
}
__device__ __forceinline__ float fast_tanh(float v) {
  float vc = fminf(fmaxf(v, -15.f), 15.f);
  float e = __expf(vc + vc);
  return (e - 1.f) * __builtin_amdgcn_rcpf(e + 1.f);
}
// XOR-swizzled LDS index (u32 elements), row stride 128 u32 = 512 B.
// Swizzle spreads 16B chunks across 8 slots -> conflict-free b128 reads & b32 writes.
__device__ __forceinline__ int xi(int r, int k) {
  return (r << 7) + (k ^ ((r & 7) << 2));
}

// ---------------------------------------------------------------------------
// Prep: split W into bf16 hi/lo planes, fragment-order, lane-major tiles.
// Tile = (ksub, mtile16): 512 bf16 laid out so lane l's 16B load at
// base + l*16 yields W[o = mt*16 + (l&15)][k = ks*32 + (l>>4)*8 + j], j=0..7.
// ---------------------------------------------------------------------------
__global__ __launch_bounds__(256) void prep_w(
    const float* __restrict__ W0, const float* __restrict__ W1,
    const float* __restrict__ W2, const float* __restrict__ W3,
    unsigned* __restrict__ ws)
{
  int t = blockIdx.x * 256 + threadIdx.x;
  if (t >= 53248) return;                 // (8 + 3*32) tiles * 512 elems
  int tile = t >> 9;
  int pos  = t & 511;
  int g = pos >> 7, o = (pos >> 3) & 15, j = pos & 7;

  const float* src; int kdim; unsigned hoff, loff; int lt;
  if (tile < 8) { src = W0; kdim = NS; hoff = O_W0H; loff = O_W0L; lt = tile; }
  else {
    int li = (tile - 8) >> 5;  lt = (tile - 8) & 31;
    src = (li == 0) ? W1 : (li == 1) ? W2 : W3;
    kdim = HID; hoff = O_WH(li); loff = O_WL(li);
  }
  int ks = (tile < 8) ? 0 : (lt >> 3);
  int mt = (tile < 8) ? lt : (lt & 7);
  int k = ks * 32 + g * 8 + j;
  int orow = mt * 16 + o;
  float v = (k < kdim) ? src[orow * kdim + k] : 0.f;
  unsigned h = f2bf_u(v);
  unsigned lo = f2bf_u(v - bf2f(h));
  int idx = lt * 512 + pos;
  ((unsigned short*)(ws + hoff))[idx] = (unsigned short)h;
  ((unsigned short*)(ws + loff))[idx] = (unsigned short)lo;
}

// ---------------------------------------------------------------------------
// One layer: X' = act(X @ W^T).  A = X from swizzled LDS (hi/lo interleaved),
// B = W from prepped global planes.  3-term bf16 split for ~fp32 accuracy.
// ---------------------------------------------------------------------------
template<int KSUBS, bool ACT>
__device__ __forceinline__ void layer(
    unsigned* __restrict__ Xs, const unsigned* __restrict__ whi,
    const unsigned* __restrict__ wlo, const float* __restrict__ bias,
    int lane, int l15, int g, int bp, int rwave, int mwave, int mt0)
{
  f4_t acc[4][4];
  #pragma unroll
  for (int a = 0; a < 4; ++a)
    #pragma unroll
    for (int b = 0; b < 4; ++b) acc[a][b] = (f4_t){0.f, 0.f, 0.f, 0.f};

  #pragma unroll
  for (int ks = 0; ks < KSUBS; ++ks) {
    // B fragments (W): coalesced 16B/lane from prepped tiles
    bf8_t bh[4], bl[4];
    #pragma unroll
    for (int mm = 0; mm < 4; ++mm) {
      int tb = (ks * 8 + mt0 + mm) * 256 + lane * 4;
      bh[mm] = __builtin_bit_cast(bf8_t, *(const uint4*)(whi + tb));
      bl[mm] = __builtin_bit_cast(bf8_t, *(const uint4*)(wlo + tb));
    }
    #pragma unroll
    for (int rs = 0; rs < 4; ++rs) {
      int r  = rwave + rs * 16 + l15;
      int k0 = ks * 32 + g * 8;
      int ia = xi(r, k0);
      uint4 q0 = *(const uint4*)(Xs + ia);
      uint4 q1 = *(const uint4*)(Xs + (ia ^ 4));
      uint4 ah, al;
      ah.x = __builtin_amdgcn_perm(q0.y, q0.x, 0x05040100u);
      ah.y = __builtin_amdgcn_perm(q0.w, q0.z, 0x05040100u);
      ah.z = __builtin_amdgcn_perm(q1.y, q1.x, 0x05040100u);
      ah.w = __builtin_amdgcn_perm(q1.w, q1.z, 0x05040100u);
      al.x = __builtin_amdgcn_perm(q0.y, q0.x, 0x07060302u);
      al.y = __builtin_amdgcn_perm(q0.w, q0.z, 0x07060302u);
      al.z = __builtin_amdgcn_perm(q1.y, q1.x, 0x07060302u);
      al.w = __builtin_amdgcn_perm(q1.w, q1.z, 0x07060302u);
      bf8_t avh = __builtin_bit_cast(bf8_t, ah);
      bf8_t avl = __builtin_bit_cast(bf8_t, al);
      #pragma unroll
      for (int mm = 0; mm < 4; ++mm) {
        acc[rs][mm] = __builtin_amdgcn_mfma_f32_16x16x32_bf16(avh, bh[mm], acc[rs][mm], 0, 0, 0);
        acc[rs][mm] = __builtin_amdgcn_mfma_f32_16x16x32_bf16(avh, bl[mm], acc[rs][mm], 0, 0, 0);
        acc[rs][mm] = __builtin_amdgcn_mfma_f32_16x16x32_bf16(avl, bh[mm], acc[rs][mm], 0, 0, 0);
      }
    }
  }
  __syncthreads();   // all reads of Xs complete -> safe to overwrite in place

  #pragma unroll
  for (int rs = 0; rs < 4; ++rs) {
    #pragma unroll
    for (int mm = 0; mm < 4; ++mm) {
      float bv = bias[mwave + mm * 16 + l15];
      f4_t a = acc[rs][mm];
      if (ACT) {
        // broadcast raw V-row value (row0 of subtile, lanes 0-15 reg0) to all
        float vb = __int_as_float(__builtin_amdgcn_ds_bpermute(bp, __float_as_int(a[0])));
        float t = fast_tanh(vb + bv);
        float s = 1.f - t * t;
        a[0] = (g == 0) ? t : a[0] * s;
        a[1] *= s; a[2] *= s; a[3] *= s;
      } else {
        if (g == 0) a[0] += bv;
      }
      int kcol = mwave + mm * 16 + l15;
      int rb = rwave + rs * 16 + g * 4;
      #pragma unroll
      for (int j = 0; j < 4; ++j) Xs[xi(rb + j, kcol)] = packhl(a[j]);
    }
  }
  __syncthreads();
}

__global__ __launch_bounds__(512, 2) void mlp_jac(
    const float* __restrict__ state,
    const float* __restrict__ safe_m, const float* __restrict__ safe_l,
    const unsigned* __restrict__ ws,
    const float* __restrict__ b0, const float* __restrict__ b1,
    const float* __restrict__ b2, const float* __restrict__ b3,
    const float* __restrict__ Wout, const float* __restrict__ bout,
    float* __restrict__ out, int bs)
{
  __shared__ unsigned Xs[RB * HID];    // 128 KB, hi|lo bf16 interleaved u32

  const int tid  = threadIdx.x;
  const int lane = tid & 63;
  const int wid  = tid >> 6;
  const int widR = wid >> 1;           // 0..3 (row groups of 64)
  const int widN = wid & 1;            // 0..1 (col groups of 64)
  const int rwave = widR * 64;
  const int mwave = widN * 64;
  const int mt0   = widN * 4;
  const int l15 = lane & 15;
  const int g   = lane >> 4;
  const int bp  = l15 * 4;             // bpermute byte addr -> lane (lane&15)
  const int s0  = blockIdx.x * SPB;

  // ---- build X0: rows 16b+0 = x_norm, 16b+(1..12) = diag(1/x_range), pad 0
  for (int i = tid; i < RB * 32; i += 512) {
    int r = i >> 5, k = i & 31;
    int b = r >> 4, rr = r & 15;
    float v = 0.f;
    if (k < NS) {
      float m = safe_m[k], l = safe_l[k];
      float inv = 2.f / (m - l);
      if (rr == 0) {
        int sidx = s0 + b;
        float sv = (sidx < bs) ? state[sidx * NS + k] : 0.f;
        v = (sv - 0.5f * (m + l)) * inv;
      } else if (rr <= NS && k == rr - 1) v = inv;
    }
    Xs[xi(r, k)] = packhl(v);
  }
  __syncthreads();

  layer<1, true >(Xs, ws + O_W0H,  ws + O_W0L,  b0, lane, l15, g, bp, rwave, mwave, mt0);
  layer<4, true >(Xs, ws + O_WH(0), ws + O_WL(0), b1, lane, l15, g, bp, rwave, mwave, mt0);
  layer<4, true >(Xs, ws + O_WH(1), ws + O_WL(1), b2, lane, l15, g, bp, rwave, mwave, mt0);
  layer<4, false>(Xs, ws + O_WH(2), ws + O_WL(2), b3, lane, l15, g, bp, rwave, mwave, mt0);

  // ---- out = Wout . X4[r,:] (+ bout on V rows); 2 threads per row
  int r = tid >> 1, half = tid & 1;
  float acc = 0.f;
  #pragma unroll
  for (int kk = 0; kk < 16; ++kk) {
    int k = half * 64 + kk * 4;
    uint4 q = *(const uint4*)(Xs + xi(r, k));
    float x0 = __uint_as_float(q.x << 16) + __uint_as_float(q.x & 0xFFFF0000u);
    float x1 = __uint_as_float(q.y << 16) + __uint_as_float(q.y & 0xFFFF0000u);
    float x2 = __uint_as_float(q.z << 16) + __uint_as_float(q.z & 0xFFFF0000u);
    float x3 = __uint_as_float(q.w << 16) + __uint_as_float(q.w & 0xFFFF0000u);
    acc = fmaf(Wout[k + 0], x0, acc);
    acc = fmaf(Wout[k + 1], x1, acc);
    acc = fmaf(Wout[k + 2], x2, acc);
    acc = fmaf(Wout[k + 3], x3, acc);
  }
  acc += __shfl_xor(acc, 1);
  if (half == 0) {
    int b = r >> 4, rr = r & 15;
    int sidx = s0 + b;
    if (sidx < bs && rr <= NS) {
      float v = acc;
      if (rr == 0) v += bout[0];
      out[sidx * 13 + rr] = v;       // rr=0 -> V, rr=1..12 -> J cols
    }
  }
}

extern "C" void kernel_launch(void* const* d_in, const int* in_sizes, int n_in,
                              void* d_out, int out_size, void* d_ws, size_t ws_size,
                              hipStream_t stream)
{
  const float* state  = (const float*)d_in[0];
  const float* safe_m = (const float*)d_in[1];
  const float* safe_l = (const float*)d_in[2];
  const float* W0   = (const float*)d_in[3];
  const float* b0   = (const float*)d_in[4];
  const float* W1   = (const float*)d_in[5];
  const float* b1   = (const float*)d_in[6];
  const float* W2   = (const float*)d_in[7];
  const float* b2   = (const float*)d_in[8];
  const float* W3   = (const float*)d_in[9];
  const float* b3   = (const float*)d_in[10];
  const float* Wout = (const float*)d_in[11];
  const float* bout = (const float*)d_in[12];
  unsigned* ws = (unsigned*)d_ws;
  float* out = (float*)d_out;

  const int bs = in_sizes[0] / NS;     // 16384

  prep_w<<<(53248 + 255) / 256, 256, 0, stream>>>(W0, W1, W2, W3, ws);

  const int nblocks = (bs + SPB - 1) / SPB;   // 1024
  mlp_jac<<<nblocks, 512, 0, stream>>>(state, safe_m, safe_l, ws,
      b0, b1, b2, b3, Wout, bout, out, bs);
}

// Round 4
// 177.987 us; speedup vs baseline: 4.9529x; 1.1644x over previous
//
#include <hip/hip_runtime.h>

#define NS  12
#define HID 128
#define SPB 8             // samples per block
#define RB  128           // rows per block = SPB*16

typedef __attribute__((ext_vector_type(8))) short bf8_t;   // 8 bf16 (4 VGPR)
typedef __attribute__((ext_vector_type(4))) float f4_t;    // C/D frag

// ws layout (u32 units): W0hi@0 (2048), W0lo@2048; W_i (i=1..3):
// hi @ 4096+(i-1)*16384 (8192), lo @ hi+8192.  Total 53248 u32 = 208 KB.
#define O_W0H 0
#define O_W0L 2048
#define O_WH(i) (4096 + (i) * 16384)
#define O_WL(i) (O_WH(i) + 8192)

__device__ __forceinline__ unsigned f2bf_u(float f) {
  unsigned u = __float_as_uint(f);
  return (u + 0x7FFFu + ((u >> 16) & 1u)) >> 16;     // RNE
}
__device__ __forceinline__ float bf2f(unsigned h) { return __uint_as_float(h << 16); }

// packed 2x f32 -> 2x bf16 (RNE). No builtin on gfx950 (T12 recipe) -> asm.
// dst lo16 = bf16(a), dst hi16 = bf16(b).
__device__ __forceinline__ unsigned cvtpk(float a, float b) {
  unsigned r;
  asm("v_cvt_pk_bf16_f32 %0, %1, %2" : "=v"(r) : "v"(a), "v"(b));
  return r;
}
__device__ __forceinline__ float fast_tanh(float v) {
  float vc = fminf(fmaxf(v, -15.f), 15.f);
  float e = __expf(vc + vc);
  return (e - 1.f) * __builtin_amdgcn_rcpf(e + 1.f);
}
__device__ __forceinline__ f4_t mfma16(bf8_t a, bf8_t b, f4_t c) {
  return __builtin_amdgcn_mfma_f32_16x16x32_bf16(a, b, c, 0, 0, 0);
}

// ---------------------------------------------------------------------------
// Prep (proven in round 2): bf16 hi/lo planes, fragment-order.
// Tile = (ksub, mtile16): lane l's 16B at base+l*16 yields
// W[o = mt*16 + (l&15)][k = ks*32 + (l>>4)*8 + j], j=0..7.
// ---------------------------------------------------------------------------
__global__ __launch_bounds__(256) void prep_w(
    const float* __restrict__ W0, const float* __restrict__ W1,
    const float* __restrict__ W2, const float* __restrict__ W3,
    unsigned* __restrict__ ws)
{
  int t = blockIdx.x * 256 + threadIdx.x;
  if (t >= 53248) return;
  int tile = t >> 9;
  int pos  = t & 511;
  int g = pos >> 7, o = (pos >> 3) & 15, j = pos & 7;

  const float* src; int kdim; unsigned hoff, loff; int lt;
  if (tile < 8) { src = W0; kdim = NS; hoff = O_W0H; loff = O_W0L; lt = tile; }
  else {
    int li = (tile - 8) >> 5;  lt = (tile - 8) & 31;
    src = (li == 0) ? W1 : (li == 1) ? W2 : W3;
    kdim = HID; hoff = O_WH(li); loff = O_WL(li);
  }
  int ks = (tile < 8) ? 0 : (lt >> 3);
  int mt = (tile < 8) ? lt : (lt & 7);
  int k = ks * 32 + g * 8 + j;
  int orow = mt * 16 + o;
  float v = (k < kdim) ? src[orow * kdim + k] : 0.f;
  unsigned h = f2bf_u(v);
  unsigned lo = f2bf_u(v - bf2f(h));
  int idx = lt * 512 + pos;
  ((unsigned short*)(ws + hoff))[idx] = (unsigned short)h;
  ((unsigned short*)(ws + loff))[idx] = (unsigned short)lo;
}

// ---------------------------------------------------------------------------
// One layer: X' = act(X @ W^T).  X in two swizzled bf16 LDS planes
// (S[0..8192) = hi words, S[8192..16384) = lo words; u32 word = 2 cols).
// ACT=false writes f32 into S (reused as [128][128] f32 for the epilogue).
// ---------------------------------------------------------------------------
template<int KSUBS, bool ACT>
__device__ __forceinline__ void layer(
    unsigned* __restrict__ S, const unsigned* __restrict__ whi,
    const unsigned* __restrict__ wlo, const float* __restrict__ bias,
    int lane, int l15, int g, int bp, int rwave, int mwave, int mt0)
{
  f4_t acc[4][2];
  #pragma unroll
  for (int a = 0; a < 4; ++a)
    #pragma unroll
    for (int b = 0; b < 2; ++b) acc[a][b] = (f4_t){0.f, 0.f, 0.f, 0.f};

  const int aswz = (l15 & 7) << 2;        // row&7 == l15&7 for A rows
  #pragma unroll
  for (int ks = 0; ks < KSUBS; ++ks) {
    bf8_t bh[2], bl[2];
    #pragma unroll
    for (int mm = 0; mm < 2; ++mm) {
      int tb = (ks * 8 + mt0 + mm) * 256 + lane * 4;
      bh[mm] = __builtin_bit_cast(bf8_t, *(const uint4*)(whi + tb));
      bl[mm] = __builtin_bit_cast(bf8_t, *(const uint4*)(wlo + tb));
    }
    #pragma unroll
    for (int rs = 0; rs < 4; ++rs) {
      int row = rwave + rs * 16 + l15;
      int idx = row * 64 + ((ks * 16 + g * 4) ^ aswz);
      bf8_t avh = __builtin_bit_cast(bf8_t, *(const uint4*)(S + idx));
      bf8_t avl = __builtin_bit_cast(bf8_t, *(const uint4*)(S + 8192 + idx));
      #pragma unroll
      for (int mm = 0; mm < 2; ++mm) {
        acc[rs][mm] = mfma16(avh, bh[mm], acc[rs][mm]);
        acc[rs][mm] = mfma16(avh, bl[mm], acc[rs][mm]);
        acc[rs][mm] = mfma16(avl, bh[mm], acc[rs][mm]);
      }
    }
  }
  __syncthreads();   // all reads done -> safe to overwrite in place

  const bool even = (lane & 1) == 0;
  #pragma unroll
  for (int rs = 0; rs < 4; ++rs) {
    #pragma unroll
    for (int mm = 0; mm < 2; ++mm) {
      int col = mwave + mm * 16 + l15;
      float bv = bias[col];
      f4_t a = acc[rs][mm];
      int rb = rwave + rs * 16 + g * 4;
      if (ACT) {
        // broadcast raw V-row value (subtile row 0: lane l15, reg 0)
        float vb = __int_as_float(__builtin_amdgcn_ds_bpermute(bp, __float_as_int(a[0])));
        float t = fast_tanh(vb + bv);
        float s = 1.f - t * t;
        a[0] = (g == 0) ? t : a[0] * s;
        a[1] *= s; a[2] *= s; a[3] *= s;
        int wc = col >> 1;
        #pragma unroll
        for (int j = 0; j < 4; ++j) {
          float pv = __shfl_xor(a[j], 1);            // quad-perm DPP
          float vlo = even ? a[j] : pv;              // even-col value
          float vhi = even ? pv : a[j];              // odd-col value
          unsigned wh = cvtpk(vlo, vhi);
          float rl = vlo - __uint_as_float(wh << 16);
          float rh = vhi - __uint_as_float(wh & 0xFFFF0000u);
          unsigned wl = cvtpk(rl, rh);
          if (even == (j < 2)) {                     // even lanes: j=0,1; odd: j=2,3
            int row = rb + j;
            int idx = row * 64 + (wc ^ ((row & 7) << 2));
            S[idx] = wh;
            S[8192 + idx] = wl;
          }
        }
      } else {
        if (g == 0) a[0] += bv;                      // V row only
        float* Xf = (float*)S;
        #pragma unroll
        for (int j = 0; j < 4; ++j) {
          int row = rb + j;
          Xf[row * 128 + (col ^ ((row & 7) << 2))] = a[j];
        }
      }
    }
  }
  __syncthreads();
}

__global__ __launch_bounds__(512, 4) void mlp_jac(
    const float* __restrict__ state,
    const float* __restrict__ safe_m, const float* __restrict__ safe_l,
    const unsigned* __restrict__ ws,
    const float* __restrict__ b0, const float* __restrict__ b1,
    const float* __restrict__ b2, const float* __restrict__ b3,
    const float* __restrict__ Wout, const float* __restrict__ bout,
    float* __restrict__ out, int bs)
{
  __shared__ unsigned S[16384];   // 64 KB: 2 bf16 planes, or 128x128 f32
  __shared__ float red[512];      // 2 KB

  const int tid  = threadIdx.x;
  const int lane = tid & 63;
  const int wid  = tid >> 6;
  const int widR = wid >> 2;          // 0..1: 64-row half
  const int widN = wid & 3;           // 0..3: 32-col group
  const int rwave = widR * 64;
  const int mwave = widN * 32;
  const int mt0   = widN * 2;
  const int l15 = lane & 15;
  const int g   = lane >> 4;
  const int bp  = l15 * 4;
  const int s0  = blockIdx.x * SPB;

  // ---- build X0 planes: rows 16b+0 = x_norm, 16b+(1..12) = diag(1/range)
  for (int i = tid; i < RB * 16; i += 512) {
    int r = i >> 4, kp = i & 15;
    int b = r >> 4, rr = r & 15;
    int sidx = s0 + b;
    float v[2];
    #pragma unroll
    for (int t = 0; t < 2; ++t) {
      int k = kp * 2 + t;
      float val = 0.f;
      if (k < NS) {
        float m = safe_m[k], l = safe_l[k];
        float inv = 2.f / (m - l);
        if (rr == 0) {
          float sv = (sidx < bs) ? state[sidx * NS + k] : 0.f;
          val = (sv - 0.5f * (m + l)) * inv;
        } else if (k == rr - 1) val = inv;
      }
      v[t] = val;
    }
    unsigned wh = cvtpk(v[0], v[1]);
    float rl = v[0] - __uint_as_float(wh << 16);
    float rh = v[1] - __uint_as_float(wh & 0xFFFF0000u);
    unsigned wl = cvtpk(rl, rh);
    int idx = r * 64 + (kp ^ ((r & 7) << 2));
    S[idx] = wh;
    S[8192 + idx] = wl;
  }
  __syncthreads();

  layer<1, true >(S, ws + O_W0H,  ws + O_W0L,  b0, lane, l15, g, bp, rwave, mwave, mt0);
  layer<4, true >(S, ws + O_WH(0), ws + O_WL(0), b1, lane, l15, g, bp, rwave, mwave, mt0);
  layer<4, true >(S, ws + O_WH(1), ws + O_WL(1), b2, lane, l15, g, bp, rwave, mwave, mt0);
  layer<4, false>(S, ws + O_WH(2), ws + O_WL(2), b3, lane, l15, g, bp, rwave, mwave, mt0);

  // ---- out = Wout . X4[r,:] (+ bout on V rows); 4 threads per row
  {
    const float* Xf = (const float*)S;
    int r = tid & 127;
    int q = tid >> 7;                 // wave-uniform -> Wout via s_load
    float a = 0.f;
    #pragma unroll
    for (int kk = 0; kk < 8; ++kk) {
      int c = q * 32 + kk * 4;
      float4 x = *(const float4*)(Xf + r * 128 + (c ^ ((r & 7) << 2)));
      a = fmaf(Wout[c + 0], x.x, a);
      a = fmaf(Wout[c + 1], x.y, a);
      a = fmaf(Wout[c + 2], x.z, a);
      a = fmaf(Wout[c + 3], x.w, a);
    }
    red[tid] = a;
  }
  __syncthreads();
  if (tid < 128) {
    float tot = red[tid] + red[tid + 128] + red[tid + 256] + red[tid + 384];
    int b = tid >> 4, rr = tid & 15;
    int sidx = s0 + b;
    if (sidx < bs && rr < 13) {
      if (rr == 0) tot += bout[0];
      out[sidx * 13 + rr] = tot;
    }
  }
}

extern "C" void kernel_launch(void* const* d_in, const int* in_sizes, int n_in,
                              void* d_out, int out_size, void* d_ws, size_t ws_size,
                              hipStream_t stream)
{
  const float* state  = (const float*)d_in[0];
  const float* safe_m = (const float*)d_in[1];
  const float* safe_l = (const float*)d_in[2];
  const float* W0   = (const float*)d_in[3];
  const float* b0   = (const float*)d_in[4];
  const float* W1   = (const float*)d_in[5];
  const float* b1   = (const float*)d_in[6];
  const float* W2   = (const float*)d_in[7];
  const float* b2   = (const float*)d_in[8];
  const float* W3   = (const float*)d_in[9];
  const float* b3   = (const float*)d_in[10];
  const float* Wout = (const float*)d_in[11];
  const float* bout = (const float*)d_in[12];
  unsigned* ws = (unsigned*)d_ws;
  float* out = (float*)d_out;

  const int bs = in_sizes[0] / NS;     // 16384

  prep_w<<<(53248 + 255) / 256, 256, 0, stream>>>(W0, W1, W2, W3, ws);

  const int nblocks = (bs + SPB - 1) / SPB;   // 2048
  mlp_jac<<<nblocks, 512, 0, stream>>>(state, safe_m, safe_l, ws,
      b0, b1, b2, b3, Wout, bout, out, bs);
}

// Round 5
// 167.911 us; speedup vs baseline: 5.2502x; 1.0600x over previous
//
#include <hip/hip_runtime.h>

#define NS  12
#define HID 128
#define SPB 8             // samples per block
#define RB  128           // rows per block = SPB*16

typedef __attribute__((ext_vector_type(8))) short bf8_t;   // 8 bf16 (4 VGPR)
typedef __attribute__((ext_vector_type(4))) float f4_t;    // C/D frag

// ws layout (u32 units): W0hi@0 (2048), W0lo@2048; W_i (i=1..3):
// hi @ 4096+(i-1)*16384 (8192), lo @ hi+8192.  Total 53248 u32 = 208 KB.
#define O_W0H 0
#define O_W0L 2048
#define O_WH(i) (4096 + (i) * 16384)
#define O_WL(i) (O_WH(i) + 8192)

__device__ __forceinline__ unsigned f2bf_u(float f) {
  unsigned u = __float_as_uint(f);
  return (u + 0x7FFFu + ((u >> 16) & 1u)) >> 16;     // RNE
}
__device__ __forceinline__ float bf2f(unsigned h) { return __uint_as_float(h << 16); }

// packed 2x f32 -> 2x bf16 (RNE). No builtin on gfx950 (T12 recipe) -> asm.
// dst lo16 = bf16(a), dst hi16 = bf16(b).
__device__ __forceinline__ unsigned cvtpk(float a, float b) {
  unsigned r;
  asm("v_cvt_pk_bf16_f32 %0, %1, %2" : "=v"(r) : "v"(a), "v"(b));
  return r;
}
__device__ __forceinline__ f4_t mfma16(bf8_t a, bf8_t b, f4_t c) {
  return __builtin_amdgcn_mfma_f32_16x16x32_bf16(a, b, c, 0, 0, 0);
}

// ---------------------------------------------------------------------------
// Prep: bf16 hi/lo planes, fragment-order (layout identical to round 4).
// Each thread produces TWO adjacent bf16 per plane -> one u32 store per plane
// (round 4's 2-byte stores suspected of sub-dword RMW slowness).
// ---------------------------------------------------------------------------
__global__ __launch_bounds__(256) void prep_w(
    const float* __restrict__ W0, const float* __restrict__ W1,
    const float* __restrict__ W2, const float* __restrict__ W3,
    unsigned* __restrict__ ws)
{
  int t = blockIdx.x * 256 + threadIdx.x;     // 104 tiles * 256 pair-slots
  if (t >= 26624) return;
  int tile = t >> 8;
  int pos  = (t & 255) * 2;                   // even element index in tile
  int g = pos >> 7, o = (pos >> 3) & 15, j = pos & 7;

  const float* src; int kdim; unsigned hoff, loff; int lt;
  if (tile < 8) { src = W0; kdim = NS; hoff = O_W0H; loff = O_W0L; lt = tile; }
  else {
    int li = (tile - 8) >> 5;  lt = (tile - 8) & 31;
    src = (li == 0) ? W1 : (li == 1) ? W2 : W3;
    kdim = HID; hoff = O_WH(li); loff = O_WL(li);
  }
  int ks = (tile < 8) ? 0 : (lt >> 3);
  int mt = (tile < 8) ? lt : (lt & 7);
  int k0 = ks * 32 + g * 8 + j;               // j even, k1 = k0+1
  int orow = mt * 16 + o;
  float v0 = (k0 < kdim)     ? src[orow * kdim + k0]     : 0.f;
  float v1 = (k0 + 1 < kdim) ? src[orow * kdim + k0 + 1] : 0.f;
  unsigned h0 = f2bf_u(v0), h1 = f2bf_u(v1);
  unsigned l0 = f2bf_u(v0 - bf2f(h0)), l1 = f2bf_u(v1 - bf2f(h1));
  int widx = (lt * 512 + pos) >> 1;           // u32 index
  (ws + hoff)[widx] = h0 | (h1 << 16);
  (ws + loff)[widx] = l0 | (l1 << 16);
}

// ---------------------------------------------------------------------------
// One layer: X' = act(X @ W^T).  X in two swizzled bf16 LDS planes
// (S[0..8192) = hi words, S[8192..16384) = lo words; u32 word = 2 cols).
// ACT=false writes f32 into S (reused as [128][128] f32 for the epilogue).
// B frags double-buffered (prefetch ks+1 during ks's MFMAs).
// ---------------------------------------------------------------------------
template<int KSUBS, bool ACT>
__device__ __forceinline__ void layer(
    unsigned* __restrict__ S, const unsigned* __restrict__ whi,
    const unsigned* __restrict__ wlo, const float* __restrict__ bias,
    int lane, int l15, int g, int bp, int rwave, int mwave, int mt0)
{
  f4_t acc[4][2];
  #pragma unroll
  for (int a = 0; a < 4; ++a)
    #pragma unroll
    for (int b = 0; b < 2; ++b) acc[a][b] = (f4_t){0.f, 0.f, 0.f, 0.f};

  const int aswz = (l15 & 7) << 2;        // row&7 == l15&7 for A rows

  bf8_t bh[2][2], bl[2][2];
  #pragma unroll
  for (int mm = 0; mm < 2; ++mm) {        // preload ks=0 B frags
    int tb = (mt0 + mm) * 256 + lane * 4;
    bh[0][mm] = __builtin_bit_cast(bf8_t, *(const uint4*)(whi + tb));
    bl[0][mm] = __builtin_bit_cast(bf8_t, *(const uint4*)(wlo + tb));
  }

  #pragma unroll
  for (int ks = 0; ks < KSUBS; ++ks) {
    const int cur = ks & 1, nxt = cur ^ 1;
    if (ks + 1 < KSUBS) {                 // prefetch next K-slice's B frags
      #pragma unroll
      for (int mm = 0; mm < 2; ++mm) {
        int tb = ((ks + 1) * 8 + mt0 + mm) * 256 + lane * 4;
        bh[nxt][mm] = __builtin_bit_cast(bf8_t, *(const uint4*)(whi + tb));
        bl[nxt][mm] = __builtin_bit_cast(bf8_t, *(const uint4*)(wlo + tb));
      }
    }
    #pragma unroll
    for (int rs = 0; rs < 4; ++rs) {
      int row = rwave + rs * 16 + l15;
      int idx = row * 64 + ((ks * 16 + g * 4) ^ aswz);
      bf8_t avh = __builtin_bit_cast(bf8_t, *(const uint4*)(S + idx));
      bf8_t avl = __builtin_bit_cast(bf8_t, *(const uint4*)(S + 8192 + idx));
      #pragma unroll
      for (int mm = 0; mm < 2; ++mm) {
        acc[rs][mm] = mfma16(avh, bh[cur][mm], acc[rs][mm]);
        acc[rs][mm] = mfma16(avh, bl[cur][mm], acc[rs][mm]);
        acc[rs][mm] = mfma16(avl, bh[cur][mm], acc[rs][mm]);
      }
    }
  }

  // hoist per-mm bias (per-lane col load, once per layer)
  float bv[2];
  #pragma unroll
  for (int mm = 0; mm < 2; ++mm) bv[mm] = bias[mwave + mm * 16 + l15];

  __syncthreads();   // all reads done -> safe to overwrite in place

  const bool ev = (lane & 1) == 0;
  #pragma unroll
  for (int rs = 0; rs < 4; ++rs) {
    int rb = rwave + rs * 16 + g * 4;
    int row0 = rb + (ev ? 0 : 2);        // this lane owns rows row0, row0+1
    int row1 = row0 + 1;
    int a0b = row0 * 64, sw0 = (row0 & 7) << 2;
    int a1b = row1 * 64, sw1 = (row1 & 7) << 2;
    #pragma unroll
    for (int mm = 0; mm < 2; ++mm) {
      int col = mwave + mm * 16 + l15;
      f4_t a = acc[rs][mm];
      if (ACT) {
        // tanh on the V-row value (subtile row 0 lives in g==0 lanes' a[0])
        float pre = a[0] + bv[mm];
        float vb = __int_as_float(__builtin_amdgcn_ds_bpermute(bp, __float_as_int(pre)));
        float e = __expf(fminf(vb, 15.f) * 2.f);
        float r = __builtin_amdgcn_rcpf(e + 1.f);
        float t = (e - 1.f) * r;
        float s = fmaf(-t, t, 1.f);
        a[0] = (g == 0) ? t : a[0] * s;
        a[1] *= s; a[2] *= s; a[3] *= s;
      } else {
        if (g == 0) a[0] += bv[mm];       // V row only
      }
      // pair adjacent columns across the lane pair (lane^1)
      float p0 = __shfl_xor(a[0], 1);
      float p1 = __shfl_xor(a[1], 1);
      float p2 = __shfl_xor(a[2], 1);
      float p3 = __shfl_xor(a[3], 1);
      float u0 = ev ? a[0] : p2;          // row0, even col
      float u1 = ev ? p0 : a[2];          // row0, odd col
      float v0 = ev ? a[1] : p3;          // row1, even col
      float v1 = ev ? p1 : a[3];          // row1, odd col
      if (ACT) {
        int wc = (mwave + mm * 16) / 2 + (l15 >> 1);
        unsigned wh0 = cvtpk(u0, u1);
        float rl0 = u0 - __uint_as_float(wh0 << 16);
        float rh0 = u1 - __uint_as_float(wh0 & 0xFFFF0000u);
        unsigned wl0 = cvtpk(rl0, rh0);
        unsigned wh1 = cvtpk(v0, v1);
        float rl1 = v0 - __uint_as_float(wh1 << 16);
        float rh1 = v1 - __uint_as_float(wh1 & 0xFFFF0000u);
        unsigned wl1 = cvtpk(rl1, rh1);
        int i0 = a0b + (wc ^ sw0);
        int i1 = a1b + (wc ^ sw1);
        S[i0] = wh0;  S[8192 + i0] = wl0;
        S[i1] = wh1;  S[8192 + i1] = wl1;
      } else {
        float* Xf = (float*)S;
        int ceven = (mwave + mm * 16) + (l15 & ~1);
        *(float2*)(Xf + row0 * 128 + (ceven ^ sw0)) = make_float2(u0, u1);
        *(float2*)(Xf + row1 * 128 + (ceven ^ sw1)) = make_float2(v0, v1);
      }
    }
  }
  __syncthreads();
}

__global__ __launch_bounds__(512, 4) void mlp_jac(
    const float* __restrict__ state,
    const float* __restrict__ safe_m, const float* __restrict__ safe_l,
    const unsigned* __restrict__ ws,
    const float* __restrict__ b0, const float* __restrict__ b1,
    const float* __restrict__ b2, const float* __restrict__ b3,
    const float* __restrict__ Wout, const float* __restrict__ bout,
    float* __restrict__ out, int bs)
{
  __shared__ unsigned S[16384];   // 64 KB: 2 bf16 planes, or 128x128 f32
  __shared__ float red[512];      // 2 KB

  const int tid  = threadIdx.x;
  const int lane = tid & 63;
  const int wid  = tid >> 6;
  const int widR = wid >> 2;          // 0..1: 64-row half
  const int widN = wid & 3;           // 0..3: 32-col group
  const int rwave = widR * 64;
  const int mwave = widN * 32;
  const int mt0   = widN * 2;
  const int l15 = lane & 15;
  const int g   = lane >> 4;
  const int bp  = l15 * 4;
  const int s0  = blockIdx.x * SPB;

  // ---- build X0 planes: rows 16b+0 = x_norm, 16b+(1..12) = diag(1/range)
  for (int i = tid; i < RB * 16; i += 512) {
    int r = i >> 4, kp = i & 15;
    int b = r >> 4, rr = r & 15;
    int sidx = s0 + b;
    float v[2];
    #pragma unroll
    for (int t = 0; t < 2; ++t) {
      int k = kp * 2 + t;
      float val = 0.f;
      if (k < NS) {
        float m = safe_m[k], l = safe_l[k];
        float inv = 2.f / (m - l);
        if (rr == 0) {
          float sv = (sidx < bs) ? state[sidx * NS + k] : 0.f;
          val = (sv - 0.5f * (m + l)) * inv;
        } else if (k == rr - 1) val = inv;
      }
      v[t] = val;
    }
    unsigned wh = cvtpk(v[0], v[1]);
    float rl = v[0] - __uint_as_float(wh << 16);
    float rh = v[1] - __uint_as_float(wh & 0xFFFF0000u);
    unsigned wl = cvtpk(rl, rh);
    int idx = r * 64 + (kp ^ ((r & 7) << 2));
    S[idx] = wh;
    S[8192 + idx] = wl;
  }
  __syncthreads();

  layer<1, true >(S, ws + O_W0H,  ws + O_W0L,  b0, lane, l15, g, bp, rwave, mwave, mt0);
  layer<4, true >(S, ws + O_WH(0), ws + O_WL(0), b1, lane, l15, g, bp, rwave, mwave, mt0);
  layer<4, true >(S, ws + O_WH(1), ws + O_WL(1), b2, lane, l15, g, bp, rwave, mwave, mt0);
  layer<4, false>(S, ws + O_WH(2), ws + O_WL(2), b3, lane, l15, g, bp, rwave, mwave, mt0);

  // ---- out = Wout . X4[r,:] (+ bout on V rows); 4 threads per row
  {
    const float* Xf = (const float*)S;
    int r = tid & 127;
    int q = tid >> 7;                 // wave-uniform -> Wout via s_load
    float a = 0.f;
    #pragma unroll
    for (int kk = 0; kk < 8; ++kk) {
      int c = q * 32 + kk * 4;
      float4 x = *(const float4*)(Xf + r * 128 + (c ^ ((r & 7) << 2)));
      a = fmaf(Wout[c + 0], x.x, a);
      a = fmaf(Wout[c + 1], x.y, a);
      a = fmaf(Wout[c + 2], x.z, a);
      a = fmaf(Wout[c + 3], x.w, a);
    }
    red[tid] = a;
  }
  __syncthreads();
  if (tid < 128) {
    float tot = red[tid] + red[tid + 128] + red[tid + 256] + red[tid + 384];
    int b = tid >> 4, rr = tid & 15;
    int sidx = s0 + b;
    if (sidx < bs && rr < 13) {
      if (rr == 0) tot += bout[0];
      out[sidx * 13 + rr] = tot;
    }
  }
}

extern "C" void kernel_launch(void* const* d_in, const int* in_sizes, int n_in,
                              void* d_out, int out_size, void* d_ws, size_t ws_size,
                              hipStream_t stream)
{
  const float* state  = (const float*)d_in[0];
  const float* safe_m = (const float*)d_in[1];
  const float* safe_l = (const float*)d_in[2];
  const float* W0   = (const float*)d_in[3];
  const float* b0   = (const float*)d_in[4];
  const float* W1   = (const float*)d_in[5];
  const float* b1   = (const float*)d_in[6];
  const float* W2   = (const float*)d_in[7];
  const float* b2   = (const float*)d_in[8];
  const float* W3   = (const float*)d_in[9];
  const float* b3   = (const float*)d_in[10];
  const float* Wout = (const float*)d_in[11];
  const float* bout = (const float*)d_in[12];
  unsigned* ws = (unsigned*)d_ws;
  float* out = (float*)d_out;

  const int bs = in_sizes[0] / NS;     // 16384

  prep_w<<<104, 256, 0, stream>>>(W0, W1, W2, W3, ws);

  const int nblocks = (bs + SPB - 1) / SPB;   // 2048
  mlp_jac<<<nblocks, 512, 0, stream>>>(state, safe_m, safe_l, ws,
      b0, b1, b2, b3, Wout, bout, out, bs);
}